// Round 11
// baseline (94.396 us; speedup 1.0000x reference)
//
#include <hip/hip_runtime.h>
#include <math.h>

// Problem constants (fixed by reference setup_inputs)
constexpr int Nn = 2, Hh = 8, Ll = 2048, Dd = 64;
constexpr int S  = Nn * Hh;      // 16 sequences
constexpr int C  = 64;           // chunk length
constexpr int NC = Ll / C;       // 32 chunks/seq
constexpr int SC = S * NC;       // 512 chunk-blocks

constexpr int SB  = 72;          // bf16 LDS row stride (144 B rows, 16B-aligned)
constexpr int SRP = 65;          // fp32 score-matrix stride
constexpr int SS8 = 9;           // stride for 8-partial row-sum scratch

#define EPSF 1e-6f
#define FLAG_MAGIC 0x5F3A9D21u

typedef __attribute__((ext_vector_type(8))) short short8;
typedef __attribute__((ext_vector_type(4))) float f32x4;
#define MFMA16(a, b, c) __builtin_amdgcn_mfma_f32_16x16x32_bf16(a, b, c, 0, 0, 0)

__device__ __forceinline__ float rcpf(float x) { return __builtin_amdgcn_rcpf(x); }
__device__ __forceinline__ float sigf(float x) { return rcpf(1.0f + __expf(-x)); }

__device__ __forceinline__ float waveRed(float v) {
#pragma unroll
    for (int off = 32; off > 0; off >>= 1) v += __shfl_xor(v, off, 64);
    return v;
}

__device__ __forceinline__ int gidx(int n, int l, int h, int d) {
    return ((n * Ll + l) * Hh + h) * Dd + d;
}

__device__ __forceinline__ float fc(const float4& v, int u) { return ((const float*)&v)[u]; }

__device__ __forceinline__ unsigned short f2bf(float x) {
    unsigned int u = __float_as_uint(x);
    unsigned int r = (u + 0x7fffu + ((u >> 16) & 1u)) >> 16;   // RNE
    return (unsigned short)r;
}
__device__ __forceinline__ unsigned int pack2(float lo, float hi) {
    return (unsigned int)f2bf(lo) | ((unsigned int)f2bf(hi) << 16);
}
__device__ __forceinline__ float bf2f(unsigned short u) {
    return __uint_as_float(((unsigned int)u) << 16);
}
__device__ __forceinline__ float lo16(unsigned int x) { return __uint_as_float(x << 16); }
__device__ __forceinline__ float hi16(unsigned int x) { return __uint_as_float(x & 0xffff0000u); }
__device__ __forceinline__ void unpack8(const uint4& v, float* o) {
    o[0] = lo16(v.x); o[1] = hi16(v.x); o[2] = lo16(v.y); o[3] = hi16(v.y);
    o[4] = lo16(v.z); o[5] = hi16(v.z); o[6] = lo16(v.w); o[7] = hi16(v.w);
}

// ---- agent-scope coherent publish/read (write-through to LLC; no cache-wide inv) ----
__device__ __forceinline__ void pubf(float* p, float v) {
    __hip_atomic_store((unsigned int*)p, __float_as_uint(v),
                       __ATOMIC_RELAXED, __HIP_MEMORY_SCOPE_AGENT);
}
__device__ __forceinline__ float rdf(const float* p) {
    return __uint_as_float(__hip_atomic_load((const unsigned int*)p,
                       __ATOMIC_RELAXED, __HIP_MEMORY_SCOPE_AGENT));
}
__device__ __forceinline__ void pubu(unsigned int* p, unsigned int v) {
    __hip_atomic_store(p, v, __ATOMIC_RELAXED, __HIP_MEMORY_SCOPE_AGENT);
}
__device__ __forceinline__ unsigned long long rd64(const void* p) {
    return __hip_atomic_load((const unsigned long long*)p,
                             __ATOMIC_RELAXED, __HIP_MEMORY_SCOPE_AGENT);
}
// All 256 threads: drain own VMEM, block-barrier, then t==0 sets the flag.
__device__ __forceinline__ void publish_flag(unsigned int* f, int t) {
    asm volatile("s_waitcnt vmcnt(0)" ::: "memory");
    __syncthreads();
    if (t == 0)
        __hip_atomic_store(f, FLAG_MAGIC, __ATOMIC_RELAXED, __HIP_MEMORY_SCOPE_AGENT);
}
// Wave 0 polls n flags at f[0..n); all waves sync after. n <= 64.
__device__ __forceinline__ void wait_n(const unsigned int* f, int n, int t) {
    if (t < 64) {
        const bool need = (t < n);
        for (;;) {
            unsigned int v = need
                ? __hip_atomic_load(&f[t], __ATOMIC_RELAXED, __HIP_MEMORY_SCOPE_AGENT)
                : FLAG_MAGIC;
            if (__all(v == FLAG_MAGIC)) break;
            __builtin_amdgcn_s_sleep(8);
        }
    }
    __syncthreads();
    asm volatile("" ::: "memory");   // no load hoisting above the poll
}

// ============================================================================
// Single persistent kernel. R10 structure plus: lookback-prefix tails in B and
// C collapsed to direct per-thread register accumulation (threads t<128 issue
// all 32 masked LLC loads for their d; group-sum order preserved -> bit-exact),
// removing one barrier + an LDS relay per layer.
// LDS 63.5 KB (static limit 64 KB). 2 blocks/CU -> all 512 co-resident.
// ============================================================================
__global__ __launch_bounds__(256, 2) void k_all(
        const float* __restrict__ Q, const float* __restrict__ K,
        const float* __restrict__ V,
        float* __restrict__ SK, float* __restrict__ SQ,
        float* __restrict__ SKso, float* __restrict__ SQsi,
        float* __restrict__ KVT, unsigned short* __restrict__ KVpb,
        float* __restrict__ Out,
        unsigned int* __restrict__ f0, unsigned int* __restrict__ f1,
        unsigned long long* __restrict__ f2, unsigned int* __restrict__ f3,
        unsigned int* __restrict__ f4) {
    __shared__ __align__(16) unsigned short sqB[C * SB];   // sigmoid(Q) rows [i][d]   (A..F)
    __shared__ __align__(16) unsigned short skB[C * SB];   // sigmoid(K) rows; F: KV-prefix rows
    __shared__ __align__(16) unsigned short vsT[C * SB];   // raw V^T [m][i]           (A..F)
    __shared__ __align__(16) unsigned short stB[C * SB];   // D: K^T; then masked P*scomp bf16
    __shared__ __align__(16) float Pun[4608];              // A: scratch; B..D: P scores
    __shared__ float scrA[C * SS8], scrB[C * SS8];
    __shared__ float colK[C], colQ[C], pk[Dd], pq[Dd];
    __shared__ float lsi[C], lso[C], rw1[C], rw2[C], le[C], ecum[C], lsc[C], s2l[C];
    __shared__ float pcsv;

    const int b = blockIdx.x, s = b / NC, c = b % NC;
    const int n = s / Hh, h = s % Hh, t = threadIdx.x;
    const int w = t >> 6, lane = t & 63, mf = lane & 15, qq = lane >> 4;
    const int I0 = 16 * w;
    float* P = Pun;

    // ---------------- Phase A: stage Q/K, publish SK/SQ ASAP ----------------
    {
        int d0 = (4 * t) & 63, ig = t >> 4;
        float psk[4] = {0, 0, 0, 0}, psq[4] = {0, 0, 0, 0};
#pragma unroll
        for (int j = 0; j < 4; j++) {
            int i = ig + 16 * j;
            int id = gidx(n, c * C + i, h, d0);
            float4 q4 = *(const float4*)&Q[id];
            float4 k4 = *(const float4*)&K[id];
            float a0 = sigf(q4.x), a1 = sigf(q4.y), a2 = sigf(q4.z), a3 = sigf(q4.w);
            float b0 = sigf(k4.x), b1 = sigf(k4.y), b2 = sigf(k4.z), b3 = sigf(k4.w);
            *(uint2*)&sqB[i * SB + d0] = make_uint2(pack2(a0, a1), pack2(a2, a3));
            *(uint2*)&skB[i * SB + d0] = make_uint2(pack2(b0, b1), pack2(b2, b3));
            psq[0] += a0; psq[1] += a1; psq[2] += a2; psq[3] += a3;
            psk[0] += b0; psk[1] += b1; psk[2] += b2; psk[3] += b3;
        }
#pragma unroll
        for (int r = 0; r < 4; r++) {
            P[ig * 64 + d0 + r] = psk[r];
            P[1024 + ig * 64 + d0 + r] = psq[r];
        }
    }
    __syncthreads();
    if (t < 64) {
        float v = 0.f;
#pragma unroll
        for (int g = 0; g < 16; g++) v += P[g * 64 + t];
        pubf(&SK[b * 64 + t], v);
    } else if (t < 128) {
        int d = t - 64; float v = 0.f;
#pragma unroll
        for (int g = 0; g < 16; g++) v += P[1024 + g * 64 + d];
        pubf(&SQ[b * 64 + d], v);
    }
    publish_flag(&f0[b], t);

    // V staging AFTER the flag (not needed until D/F)
    {
        int i0 = (t & 15) * 4, dt = (t >> 4) * 4;
        float4 vr[4];
#pragma unroll
        for (int r = 0; r < 4; r++)
            vr[r] = *(const float4*)&V[gidx(n, c * C + i0 + r, h, dt)];
#pragma unroll
        for (int u = 0; u < 4; u++)
            *(uint2*)&vsT[(dt + u) * SB + i0] = make_uint2(
                pack2(fc(vr[0], u), fc(vr[1], u)), pack2(fc(vr[2], u), fc(vr[3], u)));
    }

    // ---------------- Phase B local pre-work (flag-independent) ----------------
#pragma unroll
    for (int j = 0; j < 2; j++) {   // per-row 8-partial sums from LDS tiles
        int flat = 8 * t + 2048 * j, i = flat >> 6, d0 = flat & 63;
        uint4 xq = *(const uint4*)&sqB[i * SB + d0];
        uint4 xk = *(const uint4*)&skB[i * SB + d0];
        float qa[8], ka[8];
        unpack8(xq, qa); unpack8(xk, ka);
        float sq = 0.f, sk = 0.f;
#pragma unroll
        for (int u = 0; u < 8; u++) { sq += qa[u]; sk += ka[u]; }
        scrB[i * SS8 + (d0 >> 3)] = sq;
        scrA[i * SS8 + (d0 >> 3)] = sk;
    }
    __syncthreads();
    if (t < 64) {
        float v = 0.f;
#pragma unroll
        for (int u = 0; u < 8; u++) v += scrA[t * SS8 + u];
        colK[t] = v;
    } else if (t < 128) {
        int i = t - 64; float v = 0.f;
#pragma unroll
        for (int u = 0; u < 8; u++) v += scrB[i * SS8 + u];
        colQ[i] = v;
    }
    __syncthreads();        // colK/colQ ready

    {   // MFMA: P = sq · sk^T (kept in LDS through phase D)
        f32x4 acc[4] = {{0,0,0,0},{0,0,0,0},{0,0,0,0},{0,0,0,0}};
#pragma unroll
        for (int kk = 0; kk < 64; kk += 32) {
            short8 a = *(const short8*)&sqB[(I0 + mf) * SB + kk + qq * 8];
#pragma unroll
            for (int J = 0; J < 4; J++) {
                short8 bb = *(const short8*)&skB[(16 * J + mf) * SB + kk + qq * 8];
                acc[J] = MFMA16(a, bb, acc[J]);
            }
        }
#pragma unroll
        for (int J = 0; J < 4; J++)
#pragma unroll
            for (int r = 0; r < 4; r++)
                P[(I0 + 4 * qq + r) * SRP + 16 * J + mf] = acc[J][r];
    }
    __syncthreads();

    const int bi = t >> 2, bg = t & 3, bl = c * C + bi;
    // register-cache the sq/sk rows consumed by B's and C's dot products
    const uint4 qrow0 = *(const uint4*)&sqB[bi * SB + bg * 16];
    const uint4 qrow1 = *(const uint4*)&sqB[bi * SB + bg * 16 + 8];
    const uint4 krow0 = *(const uint4*)&skB[bi * SB + bg * 16];
    const uint4 krow1 = *(const uint4*)&skB[bi * SB + bg * 16 + 8];

    float prow[16], pcol[16];
    float r1 = 0.f, r2 = 0.f;
#pragma unroll
    for (int u = 0; u < 16; u++) {      // local triangular scans, reg-cached
        int jj = bg + 4 * u;
        prow[u] = P[bi * SRP + jj] + EPSF * colK[jj];
        pcol[u] = P[jj * SRP + bi] + EPSF * colQ[jj];
        bool ok = (jj <= bi);
        r1 += ok ? prow[u] : 0.f;
        r2 += ok ? pcol[u] : 0.f;
    }
    r1 += __shfl_xor(r1, 1, 64); r1 += __shfl_xor(r1, 2, 64);
    r2 += __shfl_xor(r2, 1, 64); r2 += __shfl_xor(r2, 2, 64);

    // ---------------- layer-0 lookback (covered by the local work above) ----------
    wait_n(&f0[s * NC], c, t);

    // ---------------- Phase B dependent tail ----------------
    // pk/pq: direct per-thread accumulation, 32 masked LLC loads each.
    // Group-accumulator order ((g0+g1)+g2)+g3 with ascending cp per group ->
    // bit-identical to the old scratch-LDS relay.
    if (t < 128) {
        const float* src = (t < 64) ? SK : SQ;
        int d = t & 63;
        float p0 = 0.f, p1 = 0.f, p2 = 0.f, p3 = 0.f;
#pragma unroll
        for (int u = 0; u < 8; u++) {
            float v0 = rdf(&src[(s * NC + (0 + 4 * u)) * 64 + d]);
            float v1 = rdf(&src[(s * NC + (1 + 4 * u)) * 64 + d]);
            float v2 = rdf(&src[(s * NC + (2 + 4 * u)) * 64 + d]);
            float v3 = rdf(&src[(s * NC + (3 + 4 * u)) * 64 + d]);
            p0 += (0 + 4 * u < c) ? v0 : 0.f;
            p1 += (1 + 4 * u < c) ? v1 : 0.f;
            p2 += (2 + 4 * u < c) ? v2 : 0.f;
            p3 += (3 + 4 * u < c) ? v3 : 0.f;
        }
        float r = ((p0 + p1) + p2) + p3;
        if (t < 64) pk[d] = r; else pq[d] = r;
    }
    __syncthreads();
    {
        float qa[16], ka[16];
        unpack8(qrow0, qa); unpack8(qrow1, qa + 8);
        unpack8(krow0, ka); unpack8(krow1, ka + 8);
        float b1 = 0.f, b2 = 0.f;
#pragma unroll
        for (int u = 0; u < 16; u++) {
            int d = bg * 16 + u;
            b1 += (qa[u] + EPSF) * (pk[d] + EPSF);
            b2 += (ka[u] + EPSF) * (pq[d] + EPSF);
        }
        b1 += __shfl_xor(b1, 1, 64); b1 += __shfl_xor(b1, 2, 64);
        b2 += __shfl_xor(b2, 1, 64); b2 += __shfl_xor(b2, 2, 64);
        if (bg == 0) {
            float nf = (float)(bl + 1);
            lsi[bi] = nf * rcpf(b1 + r1);
            lso[bi] = nf * rcpf(b2 + r2);
        }
    }
    __syncthreads();
    {   // SKso/SQsi -> publish (flag first; rw1/rw2 moved off-path below)
        int d = t >> 2, g = t & 3;
        float v1 = 0.f, v2 = 0.f;
#pragma unroll
        for (int u = 0; u < 16; u++) {
            int i = g * 16 + u;
            v1 += bf2f(skB[i * SB + d]) * lso[i];
            v2 += bf2f(sqB[i * SB + d]) * lsi[i];
        }
        v1 += __shfl_xor(v1, 1, 64); v1 += __shfl_xor(v1, 2, 64);
        v2 += __shfl_xor(v2, 1, 64); v2 += __shfl_xor(v2, 2, 64);
        if (g == 0) {
            pubf(&SKso[b * 64 + d], v1);
            pubf(&SQsi[b * 64 + d], v2);
        }
    }
    publish_flag(&f1[b], t);

    {   // rw1/rw2 from cached registers (local; covers the f1-layer wait)
        float a1 = 0.f, a2 = 0.f;
#pragma unroll
        for (int u = 0; u < 16; u++) {
            int jj = bg + 4 * u;
            float t1 = lso[jj] * prow[u];
            float t2 = lsi[jj] * pcol[u];
            bool ok = (jj <= bi);
            a1 += ok ? t1 : 0.f;
            a2 += ok ? t2 : 0.f;
        }
        a1 += __shfl_xor(a1, 1, 64); a1 += __shfl_xor(a1, 2, 64);
        a2 += __shfl_xor(a2, 1, 64); a2 += __shfl_xor(a2, 2, 64);
        if (bg == 0) { rw1[bi] = a1; rw2[bi] = a2; }
    }

    // ---------------- layer-1 lookback ----------------
    wait_n(&f1[s * NC], c, t);

    // ---------------- Phase C: cs/csr, e, s2, ecum; Tcs packed into f2 ----------------
    if (t < 128) {      // pk/pq from SKso/SQsi: direct accumulation (same order)
        const float* src = (t < 64) ? SKso : SQsi;
        int d = t & 63;
        float p0 = 0.f, p1 = 0.f, p2 = 0.f, p3 = 0.f;
#pragma unroll
        for (int u = 0; u < 8; u++) {
            float v0 = rdf(&src[(s * NC + (0 + 4 * u)) * 64 + d]);
            float v1 = rdf(&src[(s * NC + (1 + 4 * u)) * 64 + d]);
            float v2 = rdf(&src[(s * NC + (2 + 4 * u)) * 64 + d]);
            float v3 = rdf(&src[(s * NC + (3 + 4 * u)) * 64 + d]);
            p0 += (0 + 4 * u < c) ? v0 : 0.f;
            p1 += (1 + 4 * u < c) ? v1 : 0.f;
            p2 += (2 + 4 * u < c) ? v2 : 0.f;
            p3 += (3 + 4 * u < c) ? v3 : 0.f;
        }
        float r = ((p0 + p1) + p2) + p3;
        if (t < 64) pk[d] = r; else pq[d] = r;
    }
    __syncthreads();
    {
        float qa[16], ka[16];
        unpack8(qrow0, qa); unpack8(qrow1, qa + 8);
        unpack8(krow0, ka); unpack8(krow1, ka + 8);
        float b1 = 0.f, b2 = 0.f;
#pragma unroll
        for (int u = 0; u < 16; u++) {
            int d = bg * 16 + u;
            b1 += (qa[u] + EPSF) * (pk[d] + EPSF);
            b2 += (ka[u] + EPSF) * (pq[d] + EPSF);
        }
        b1 += __shfl_xor(b1, 1, 64); b1 += __shfl_xor(b1, 2, 64);
        b2 += __shfl_xor(b2, 1, 64); b2 += __shfl_xor(b2, 2, 64);
        if (bg == 0) {
            float nf = (float)(bl + 1);
            float cs  = (b1 + rw1[bi]) * rcpf(nf);
            float csr = (b2 + rw2[bi]) * rcpf(nf);
            csr = fminf(fmaxf(csr, -1.f), 1.f);
            float e = __expf(csr);
            float sal = sigf(cs);
            s2l[bi] = lsi[bi] * rcpf(nf) * sal;
            le[bi] = e;
        }
    }
    __syncthreads();
    if (t < 64) {           // inclusive chunk-local scan of e
        float run = le[t];
#pragma unroll
        for (int off = 1; off < 64; off <<= 1) {
            float o = __shfl_up(run, off, 64);
            if (t >= off) run += o;
        }
        ecum[t] = run;
    }
    __syncthreads();
    if (t == 0) {           // publish {MAGIC, Tcs} as one u64 flag (LDS-sourced, no drain)
        unsigned long long pv = ((unsigned long long)FLAG_MAGIC << 32)
                              | (unsigned long long)__float_as_uint(ecum[63]);
        __hip_atomic_store(&f2[b], pv, __ATOMIC_RELAXED, __HIP_MEMORY_SCOPE_AGENT);
    }

    // local work covering the layer-2 wait: skB -> K^T transpose into stB
    {
        int i0 = (t & 15) * 4, dt = (t >> 4) * 4;
        uint2 kr[4];
#pragma unroll
        for (int r = 0; r < 4; r++) kr[r] = *(const uint2*)&skB[(i0 + r) * SB + dt];
#pragma unroll
        for (int u = 0; u < 4; u++) {
            unsigned int e0 = (u < 2 ? kr[0].x : kr[0].y), e1 = (u < 2 ? kr[1].x : kr[1].y);
            unsigned int e2 = (u < 2 ? kr[2].x : kr[2].y), e3 = (u < 2 ? kr[3].x : kr[3].y);
            int sh = (u & 1) * 16;
            unsigned int lo = ((e0 >> sh) & 0xffffu) | (((e1 >> sh) & 0xffffu) << 16);
            unsigned int hi = ((e2 >> sh) & 0xffffu) | (((e3 >> sh) & 0xffffu) << 16);
            *(uint2*)&stB[(dt + u) * SB + i0] = make_uint2(lo, hi);
        }
    }

    // ---------------- layer-2 lookback: poll returns Tcs values directly -------------
    if (t < 64) {
        bool need = (t < c);
        float tv = 0.f;
        for (;;) {
            unsigned long long x = need
                ? __hip_atomic_load(&f2[s * NC + t], __ATOMIC_RELAXED, __HIP_MEMORY_SCOPE_AGENT)
                : ((unsigned long long)FLAG_MAGIC << 32);
            if (__all((unsigned int)(x >> 32) == FLAG_MAGIC)) {
                tv = need ? __uint_as_float((unsigned int)x) : 0.f;
                break;
            }
            __builtin_amdgcn_s_sleep(8);
        }
        float v = waveRed(tv);          // same lane values -> bit-identical pcsv
        if (t == 0) pcsv = v;
    }
    __syncthreads();
    asm volatile("" ::: "memory");

    // ---------------- Phase D: lsc -> KVT MFMA (inline-scaled A) -> f3 ----------------
    if (t < 64) {
        int l = c * C + t;
        lsc[t] = le[t] * rcpf(pcsv + ecum[t]) * (float)(l + 1);
    }
    __syncthreads();

    {   // MFMA: KVT[m][d] = sum_i bf16(vraw[m][i]*lsc[i]) * K^T[d][i]; A scaled inline
        f32x4 acc[4] = {{0,0,0,0},{0,0,0,0},{0,0,0,0},{0,0,0,0}};
#pragma unroll
        for (int kk = 0; kk < 64; kk += 32) {
            short8 av = *(const short8*)&vsT[(I0 + mf) * SB + kk + qq * 8];
            short8 a;
#pragma unroll
            for (int u = 0; u < 8; u++)
                a[u] = (short)f2bf(bf2f((unsigned short)av[u]) * lsc[kk + qq * 8 + u]);
#pragma unroll
            for (int J = 0; J < 4; J++) {
                short8 bb = *(const short8*)&stB[(16 * J + mf) * SB + kk + qq * 8];
                acc[J] = MFMA16(a, bb, acc[J]);
            }
        }
#pragma unroll
        for (int J = 0; J < 4; J++)
#pragma unroll
            for (int r = 0; r < 4; r++)
                pubf(&KVT[(size_t)b * 4096 + (I0 + 4 * qq + r) * 64 + 16 * J + mf],
                     acc[J][r]);
    }
    publish_flag(&f3[b], t);

    {   // masked P*scomp -> stB (overwrites K^T; fenced by f3's barrier; overlaps E)
        int i = t >> 2, g = t & 3;
        unsigned int wds[8];
#pragma unroll
        for (int p = 0; p < 8; p++) {
            int j0 = g * 16 + 2 * p;
            float v0 = (j0     <= i) ? P[i * SRP + j0]     * lsc[j0]     : 0.f;
            float v1 = (j0 + 1 <= i) ? P[i * SRP + j0 + 1] * lsc[j0 + 1] : 0.f;
            wds[p] = pack2(v0, v1);
        }
        *(uint4*)&stB[i * SB + g * 16]     = make_uint4(wds[0], wds[1], wds[2], wds[3]);
        *(uint4*)&stB[i * SB + g * 16 + 8] = make_uint4(wds[4], wds[5], wds[6], wds[7]);
    }
    __syncthreads();

    // ---------------- Phase E: KVT exclusive prefix, slice c of OWN seq (c<8) --------
    if (c < 8) {
        wait_n(&f3[s * NC], NC, t);
        int e0 = c * 512 + 2 * t;
        float2 x[NC];
#pragma unroll
        for (int cp = 0; cp < NC; cp++) {
            unsigned long long v = rd64(&KVT[(size_t)(s * NC + cp) * 4096 + e0]);
            x[cp].x = __uint_as_float((unsigned int)v);
            x[cp].y = __uint_as_float((unsigned int)(v >> 32));
        }
        float r0 = 0.f, r1p = 0.f;
#pragma unroll
        for (int cp = 0; cp < NC; cp++) {
            pubu((unsigned int*)&KVpb[(size_t)(s * NC + cp) * 4096 + e0], pack2(r0, r1p));
            r0 += x[cp].x; r1p += x[cp].y;
        }
        publish_flag(&f4[s * 8 + c], t);
    }

    // ---------------- Phase F: local mm2 first, then wait + mm1 ----------------
    f32x4 acc[4] = {{0,0,0,0},{0,0,0,0},{0,0,0,0},{0,0,0,0}};
#pragma unroll
    for (int kk = 0; kk < 64; kk += 32) {   // mm2: stB(masked P*scomp) · v  (local)
        short8 a2 = *(const short8*)&stB[(I0 + mf) * SB + kk + qq * 8];
#pragma unroll
        for (int J = 0; J < 4; J++) {
            short8 b2 = *(const short8*)&vsT[(16 * J + mf) * SB + kk + qq * 8];
            acc[J] = MFMA16(a2, b2, acc[J]);
        }
    }

    wait_n(&f4[8 * s], 8, t);
    {
        unsigned long long kvp[4];
        size_t base = (size_t)b * 4096;
#pragma unroll
        for (int j = 0; j < 2; j++) {
            kvp[2 * j]     = rd64(&KVpb[base + 8 * t + 2048 * j]);
            kvp[2 * j + 1] = rd64(&KVpb[base + 8 * t + 2048 * j + 4]);
        }
#pragma unroll
        for (int j = 0; j < 2; j++) {   // overlay KV-prefix rows [m][d] onto skB
            int flat = 8 * t + 2048 * j, i = flat >> 6, d0 = flat & 63;
            *(uint2*)&skB[i * SB + d0] =
                make_uint2((unsigned int)kvp[2 * j], (unsigned int)(kvp[2 * j] >> 32));
            *(uint2*)&skB[i * SB + d0 + 4] =
                make_uint2((unsigned int)kvp[2 * j + 1], (unsigned int)(kvp[2 * j + 1] >> 32));
        }
    }
    __syncthreads();

#pragma unroll
    for (int kk = 0; kk < 64; kk += 32) {   // mm1: sq · KVp
        short8 a1 = *(const short8*)&sqB[(I0 + mf) * SB + kk + qq * 8];
#pragma unroll
        for (int J = 0; J < 4; J++) {
            short8 b1 = *(const short8*)&skB[(16 * J + mf) * SB + kk + qq * 8];
            acc[J] = MFMA16(a1, b1, acc[J]);
        }
    }
#pragma unroll
    for (int J = 0; J < 4; J++)
#pragma unroll
        for (int r = 0; r < 4; r++) {
            int io = I0 + 4 * qq + r;
            Out[gidx(n, c * C + io, h, 16 * J + mf)] = acc[J][r] * s2l[io];
        }
}

extern "C" void kernel_launch(void* const* d_in, const int* in_sizes, int n_in,
                              void* d_out, int out_size, void* d_ws, size_t ws_size,
                              hipStream_t stream) {
    const float* Q = (const float*)d_in[0];
    const float* K = (const float*)d_in[1];
    const float* V = (const float*)d_in[2];
    float* Out = (float*)d_out;

    float* ws   = (float*)d_ws;
    float* SK   = ws;                   // SC*64
    float* SQ   = SK   + SC * 64;
    float* SKso = SQ   + SC * 64;
    float* SQsi = SKso + SC * 64;
    float* KVT  = SQsi + SC * 64;       // SC*4096 f32
    unsigned short* KVpb = (unsigned short*)(KVT + (size_t)SC * 4096);  // SC*4096 bf16
    unsigned long long* f2 = (unsigned long long*)(KVpb + (size_t)SC * 4096); // SC u64
    unsigned int* f0 = (unsigned int*)(f2 + SC);    // SC each
    unsigned int* f1 = f0 + SC;
    unsigned int* f3 = f1 + SC;
    unsigned int* f4 = f3 + SC;         // 128 used

    k_all<<<SC, 256, 0, stream>>>(Q, K, V, SK, SQ, SKso, SQsi, KVT, KVpb, Out,
                                  f0, f1, f2, f3, f4);
}

// Round 12
// 90.972 us; speedup vs baseline: 1.0376x; 1.0376x over previous
//
#include <hip/hip_runtime.h>
#include <math.h>

// Problem constants (fixed by reference setup_inputs)
constexpr int Nn = 2, Hh = 8, Ll = 2048, Dd = 64;
constexpr int S  = Nn * Hh;      // 16 sequences
constexpr int C  = 64;           // chunk length
constexpr int NC = Ll / C;       // 32 chunks/seq
constexpr int SC = S * NC;       // 512 chunk-blocks

constexpr int SB  = 72;          // bf16 LDS row stride (144 B rows, 16B-aligned)
constexpr int SRP = 65;          // fp32 score-matrix stride
constexpr int SS8 = 9;           // stride for 8-partial row-sum scratch

#define EPSF 1e-6f
#define FLAG_MAGIC 0x5F3A9D21u

typedef __attribute__((ext_vector_type(8))) short short8;
typedef __attribute__((ext_vector_type(4))) float f32x4;
#define MFMA16(a, b, c) __builtin_amdgcn_mfma_f32_16x16x32_bf16(a, b, c, 0, 0, 0)

__device__ __forceinline__ float rcpf(float x) { return __builtin_amdgcn_rcpf(x); }
__device__ __forceinline__ float sigf(float x) { return rcpf(1.0f + __expf(-x)); }

__device__ __forceinline__ float waveRed(float v) {
#pragma unroll
    for (int off = 32; off > 0; off >>= 1) v += __shfl_xor(v, off, 64);
    return v;
}

__device__ __forceinline__ int gidx(int n, int l, int h, int d) {
    return ((n * Ll + l) * Hh + h) * Dd + d;
}

__device__ __forceinline__ float fc(const float4& v, int u) { return ((const float*)&v)[u]; }

__device__ __forceinline__ unsigned short f2bf(float x) {
    unsigned int u = __float_as_uint(x);
    unsigned int r = (u + 0x7fffu + ((u >> 16) & 1u)) >> 16;   // RNE
    return (unsigned short)r;
}
__device__ __forceinline__ unsigned int pack2(float lo, float hi) {
    return (unsigned int)f2bf(lo) | ((unsigned int)f2bf(hi) << 16);
}
__device__ __forceinline__ float bf2f(unsigned short u) {
    return __uint_as_float(((unsigned int)u) << 16);
}
__device__ __forceinline__ float lo16(unsigned int x) { return __uint_as_float(x << 16); }
__device__ __forceinline__ float hi16(unsigned int x) { return __uint_as_float(x & 0xffff0000u); }
__device__ __forceinline__ void unpack8(const uint4& v, float* o) {
    o[0] = lo16(v.x); o[1] = hi16(v.x); o[2] = lo16(v.y); o[3] = hi16(v.y);
    o[4] = lo16(v.z); o[5] = hi16(v.z); o[6] = lo16(v.w); o[7] = hi16(v.w);
}

// ---- agent-scope coherent publish/read (write-through to LLC; no cache-wide inv) ----
__device__ __forceinline__ void pubf(float* p, float v) {
    __hip_atomic_store((unsigned int*)p, __float_as_uint(v),
                       __ATOMIC_RELAXED, __HIP_MEMORY_SCOPE_AGENT);
}
__device__ __forceinline__ float rdf(const float* p) {
    return __uint_as_float(__hip_atomic_load((const unsigned int*)p,
                       __ATOMIC_RELAXED, __HIP_MEMORY_SCOPE_AGENT));
}
__device__ __forceinline__ void pubu(unsigned int* p, unsigned int v) {
    __hip_atomic_store(p, v, __ATOMIC_RELAXED, __HIP_MEMORY_SCOPE_AGENT);
}
__device__ __forceinline__ unsigned long long rd64(const void* p) {
    return __hip_atomic_load((const unsigned long long*)p,
                             __ATOMIC_RELAXED, __HIP_MEMORY_SCOPE_AGENT);
}
// All 256 threads: drain own VMEM, block-barrier, then t==0 sets the flag.
__device__ __forceinline__ void publish_flag(unsigned int* f, int t) {
    asm volatile("s_waitcnt vmcnt(0)" ::: "memory");
    __syncthreads();
    if (t == 0)
        __hip_atomic_store(f, FLAG_MAGIC, __ATOMIC_RELAXED, __HIP_MEMORY_SCOPE_AGENT);
}
// Wave 0 polls n flags at f[0..n); all waves sync after. n <= 64.
__device__ __forceinline__ void wait_n(const unsigned int* f, int n, int t) {
    if (t < 64) {
        const bool need = (t < n);
        for (;;) {
            unsigned int v = need
                ? __hip_atomic_load(&f[t], __ATOMIC_RELAXED, __HIP_MEMORY_SCOPE_AGENT)
                : FLAG_MAGIC;
            if (__all(v == FLAG_MAGIC)) break;
            __builtin_amdgcn_s_sleep(2);
        }
    }
    __syncthreads();
    asm volatile("" ::: "memory");   // no load hoisting above the poll
}

// ============================================================================
// Single persistent kernel. R11 structure plus: phase E spread over ALL 32
// blocks per sequence (128-elem slice each; f4 = one flag per block, F waits
// n=32); F's local mm2 moved before the f3-all wait (covers the straggler
// window); c=0 skips the f4 wait (its prefix rows are exactly pack2(0,0));
// poll sleep 8 -> 2 (finer detection).
// LDS 63.5 KB (static limit 64 KB). 2 blocks/CU -> all 512 co-resident.
// ============================================================================
__global__ __launch_bounds__(256, 2) void k_all(
        const float* __restrict__ Q, const float* __restrict__ K,
        const float* __restrict__ V,
        float* __restrict__ SK, float* __restrict__ SQ,
        float* __restrict__ SKso, float* __restrict__ SQsi,
        float* __restrict__ KVT, unsigned short* __restrict__ KVpb,
        float* __restrict__ Out,
        unsigned int* __restrict__ f0, unsigned int* __restrict__ f1,
        unsigned long long* __restrict__ f2, unsigned int* __restrict__ f3,
        unsigned int* __restrict__ f4) {
    __shared__ __align__(16) unsigned short sqB[C * SB];   // sigmoid(Q) rows [i][d]   (A..F)
    __shared__ __align__(16) unsigned short skB[C * SB];   // sigmoid(K) rows; F: KV-prefix rows
    __shared__ __align__(16) unsigned short vsT[C * SB];   // raw V^T [m][i]           (A..F)
    __shared__ __align__(16) unsigned short stB[C * SB];   // D: K^T; then masked P*scomp bf16
    __shared__ __align__(16) float Pun[4608];              // A: scratch; B..D: P scores
    __shared__ float scrA[C * SS8], scrB[C * SS8];
    __shared__ float colK[C], colQ[C], pk[Dd], pq[Dd];
    __shared__ float lsi[C], lso[C], rw1[C], rw2[C], le[C], ecum[C], lsc[C], s2l[C];
    __shared__ float pcsv;

    const int b = blockIdx.x, s = b / NC, c = b % NC;
    const int n = s / Hh, h = s % Hh, t = threadIdx.x;
    const int w = t >> 6, lane = t & 63, mf = lane & 15, qq = lane >> 4;
    const int I0 = 16 * w;
    float* P = Pun;

    // ---------------- Phase A: stage Q/K, publish SK/SQ ASAP ----------------
    {
        int d0 = (4 * t) & 63, ig = t >> 4;
        float psk[4] = {0, 0, 0, 0}, psq[4] = {0, 0, 0, 0};
#pragma unroll
        for (int j = 0; j < 4; j++) {
            int i = ig + 16 * j;
            int id = gidx(n, c * C + i, h, d0);
            float4 q4 = *(const float4*)&Q[id];
            float4 k4 = *(const float4*)&K[id];
            float a0 = sigf(q4.x), a1 = sigf(q4.y), a2 = sigf(q4.z), a3 = sigf(q4.w);
            float b0 = sigf(k4.x), b1 = sigf(k4.y), b2 = sigf(k4.z), b3 = sigf(k4.w);
            *(uint2*)&sqB[i * SB + d0] = make_uint2(pack2(a0, a1), pack2(a2, a3));
            *(uint2*)&skB[i * SB + d0] = make_uint2(pack2(b0, b1), pack2(b2, b3));
            psq[0] += a0; psq[1] += a1; psq[2] += a2; psq[3] += a3;
            psk[0] += b0; psk[1] += b1; psk[2] += b2; psk[3] += b3;
        }
#pragma unroll
        for (int r = 0; r < 4; r++) {
            P[ig * 64 + d0 + r] = psk[r];
            P[1024 + ig * 64 + d0 + r] = psq[r];
        }
    }
    __syncthreads();
    if (t < 64) {
        float v = 0.f;
#pragma unroll
        for (int g = 0; g < 16; g++) v += P[g * 64 + t];
        pubf(&SK[b * 64 + t], v);
    } else if (t < 128) {
        int d = t - 64; float v = 0.f;
#pragma unroll
        for (int g = 0; g < 16; g++) v += P[1024 + g * 64 + d];
        pubf(&SQ[b * 64 + d], v);
    }
    publish_flag(&f0[b], t);

    // V staging AFTER the flag (not needed until D/F)
    {
        int i0 = (t & 15) * 4, dt = (t >> 4) * 4;
        float4 vr[4];
#pragma unroll
        for (int r = 0; r < 4; r++)
            vr[r] = *(const float4*)&V[gidx(n, c * C + i0 + r, h, dt)];
#pragma unroll
        for (int u = 0; u < 4; u++)
            *(uint2*)&vsT[(dt + u) * SB + i0] = make_uint2(
                pack2(fc(vr[0], u), fc(vr[1], u)), pack2(fc(vr[2], u), fc(vr[3], u)));
    }

    // ---------------- Phase B local pre-work (flag-independent) ----------------
#pragma unroll
    for (int j = 0; j < 2; j++) {   // per-row 8-partial sums from LDS tiles
        int flat = 8 * t + 2048 * j, i = flat >> 6, d0 = flat & 63;
        uint4 xq = *(const uint4*)&sqB[i * SB + d0];
        uint4 xk = *(const uint4*)&skB[i * SB + d0];
        float qa[8], ka[8];
        unpack8(xq, qa); unpack8(xk, ka);
        float sq = 0.f, sk = 0.f;
#pragma unroll
        for (int u = 0; u < 8; u++) { sq += qa[u]; sk += ka[u]; }
        scrB[i * SS8 + (d0 >> 3)] = sq;
        scrA[i * SS8 + (d0 >> 3)] = sk;
    }
    __syncthreads();
    if (t < 64) {
        float v = 0.f;
#pragma unroll
        for (int u = 0; u < 8; u++) v += scrA[t * SS8 + u];
        colK[t] = v;
    } else if (t < 128) {
        int i = t - 64; float v = 0.f;
#pragma unroll
        for (int u = 0; u < 8; u++) v += scrB[i * SS8 + u];
        colQ[i] = v;
    }
    __syncthreads();        // colK/colQ ready

    {   // MFMA: P = sq · sk^T (kept in LDS through phase D)
        f32x4 acc[4] = {{0,0,0,0},{0,0,0,0},{0,0,0,0},{0,0,0,0}};
#pragma unroll
        for (int kk = 0; kk < 64; kk += 32) {
            short8 a = *(const short8*)&sqB[(I0 + mf) * SB + kk + qq * 8];
#pragma unroll
            for (int J = 0; J < 4; J++) {
                short8 bb = *(const short8*)&skB[(16 * J + mf) * SB + kk + qq * 8];
                acc[J] = MFMA16(a, bb, acc[J]);
            }
        }
#pragma unroll
        for (int J = 0; J < 4; J++)
#pragma unroll
            for (int r = 0; r < 4; r++)
                P[(I0 + 4 * qq + r) * SRP + 16 * J + mf] = acc[J][r];
    }
    __syncthreads();

    const int bi = t >> 2, bg = t & 3, bl = c * C + bi;
    // register-cache the sq/sk rows consumed by B's and C's dot products
    const uint4 qrow0 = *(const uint4*)&sqB[bi * SB + bg * 16];
    const uint4 qrow1 = *(const uint4*)&sqB[bi * SB + bg * 16 + 8];
    const uint4 krow0 = *(const uint4*)&skB[bi * SB + bg * 16];
    const uint4 krow1 = *(const uint4*)&skB[bi * SB + bg * 16 + 8];

    float prow[16], pcol[16];
    float r1 = 0.f, r2 = 0.f;
#pragma unroll
    for (int u = 0; u < 16; u++) {      // local triangular scans, reg-cached
        int jj = bg + 4 * u;
        prow[u] = P[bi * SRP + jj] + EPSF * colK[jj];
        pcol[u] = P[jj * SRP + bi] + EPSF * colQ[jj];
        bool ok = (jj <= bi);
        r1 += ok ? prow[u] : 0.f;
        r2 += ok ? pcol[u] : 0.f;
    }
    r1 += __shfl_xor(r1, 1, 64); r1 += __shfl_xor(r1, 2, 64);
    r2 += __shfl_xor(r2, 1, 64); r2 += __shfl_xor(r2, 2, 64);

    // ---------------- layer-0 lookback (covered by the local work above) ----------
    wait_n(&f0[s * NC], c, t);

    // ---------------- Phase B dependent tail ----------------
    // pk/pq: direct per-thread accumulation, 32 masked LLC loads each.
    if (t < 128) {
        const float* src = (t < 64) ? SK : SQ;
        int d = t & 63;
        float p0 = 0.f, p1 = 0.f, p2 = 0.f, p3 = 0.f;
#pragma unroll
        for (int u = 0; u < 8; u++) {
            float v0 = rdf(&src[(s * NC + (0 + 4 * u)) * 64 + d]);
            float v1 = rdf(&src[(s * NC + (1 + 4 * u)) * 64 + d]);
            float v2 = rdf(&src[(s * NC + (2 + 4 * u)) * 64 + d]);
            float v3 = rdf(&src[(s * NC + (3 + 4 * u)) * 64 + d]);
            p0 += (0 + 4 * u < c) ? v0 : 0.f;
            p1 += (1 + 4 * u < c) ? v1 : 0.f;
            p2 += (2 + 4 * u < c) ? v2 : 0.f;
            p3 += (3 + 4 * u < c) ? v3 : 0.f;
        }
        float r = ((p0 + p1) + p2) + p3;
        if (t < 64) pk[d] = r; else pq[d] = r;
    }
    __syncthreads();
    {
        float qa[16], ka[16];
        unpack8(qrow0, qa); unpack8(qrow1, qa + 8);
        unpack8(krow0, ka); unpack8(krow1, ka + 8);
        float b1 = 0.f, b2 = 0.f;
#pragma unroll
        for (int u = 0; u < 16; u++) {
            int d = bg * 16 + u;
            b1 += (qa[u] + EPSF) * (pk[d] + EPSF);
            b2 += (ka[u] + EPSF) * (pq[d] + EPSF);
        }
        b1 += __shfl_xor(b1, 1, 64); b1 += __shfl_xor(b1, 2, 64);
        b2 += __shfl_xor(b2, 1, 64); b2 += __shfl_xor(b2, 2, 64);
        if (bg == 0) {
            float nf = (float)(bl + 1);
            lsi[bi] = nf * rcpf(b1 + r1);
            lso[bi] = nf * rcpf(b2 + r2);
        }
    }
    __syncthreads();
    {   // SKso/SQsi -> publish (flag first; rw1/rw2 moved off-path below)
        int d = t >> 2, g = t & 3;
        float v1 = 0.f, v2 = 0.f;
#pragma unroll
        for (int u = 0; u < 16; u++) {
            int i = g * 16 + u;
            v1 += bf2f(skB[i * SB + d]) * lso[i];
            v2 += bf2f(sqB[i * SB + d]) * lsi[i];
        }
        v1 += __shfl_xor(v1, 1, 64); v1 += __shfl_xor(v1, 2, 64);
        v2 += __shfl_xor(v2, 1, 64); v2 += __shfl_xor(v2, 2, 64);
        if (g == 0) {
            pubf(&SKso[b * 64 + d], v1);
            pubf(&SQsi[b * 64 + d], v2);
        }
    }
    publish_flag(&f1[b], t);

    {   // rw1/rw2 from cached registers (local; covers the f1-layer wait)
        float a1 = 0.f, a2 = 0.f;
#pragma unroll
        for (int u = 0; u < 16; u++) {
            int jj = bg + 4 * u;
            float t1 = lso[jj] * prow[u];
            float t2 = lsi[jj] * pcol[u];
            bool ok = (jj <= bi);
            a1 += ok ? t1 : 0.f;
            a2 += ok ? t2 : 0.f;
        }
        a1 += __shfl_xor(a1, 1, 64); a1 += __shfl_xor(a1, 2, 64);
        a2 += __shfl_xor(a2, 1, 64); a2 += __shfl_xor(a2, 2, 64);
        if (bg == 0) { rw1[bi] = a1; rw2[bi] = a2; }
    }

    // ---------------- layer-1 lookback ----------------
    wait_n(&f1[s * NC], c, t);

    // ---------------- Phase C: cs/csr, e, s2, ecum; Tcs packed into f2 ----------------
    if (t < 128) {      // pk/pq from SKso/SQsi: direct accumulation (same order)
        const float* src = (t < 64) ? SKso : SQsi;
        int d = t & 63;
        float p0 = 0.f, p1 = 0.f, p2 = 0.f, p3 = 0.f;
#pragma unroll
        for (int u = 0; u < 8; u++) {
            float v0 = rdf(&src[(s * NC + (0 + 4 * u)) * 64 + d]);
            float v1 = rdf(&src[(s * NC + (1 + 4 * u)) * 64 + d]);
            float v2 = rdf(&src[(s * NC + (2 + 4 * u)) * 64 + d]);
            float v3 = rdf(&src[(s * NC + (3 + 4 * u)) * 64 + d]);
            p0 += (0 + 4 * u < c) ? v0 : 0.f;
            p1 += (1 + 4 * u < c) ? v1 : 0.f;
            p2 += (2 + 4 * u < c) ? v2 : 0.f;
            p3 += (3 + 4 * u < c) ? v3 : 0.f;
        }
        float r = ((p0 + p1) + p2) + p3;
        if (t < 64) pk[d] = r; else pq[d] = r;
    }
    __syncthreads();
    {
        float qa[16], ka[16];
        unpack8(qrow0, qa); unpack8(qrow1, qa + 8);
        unpack8(krow0, ka); unpack8(krow1, ka + 8);
        float b1 = 0.f, b2 = 0.f;
#pragma unroll
        for (int u = 0; u < 16; u++) {
            int d = bg * 16 + u;
            b1 += (qa[u] + EPSF) * (pk[d] + EPSF);
            b2 += (ka[u] + EPSF) * (pq[d] + EPSF);
        }
        b1 += __shfl_xor(b1, 1, 64); b1 += __shfl_xor(b1, 2, 64);
        b2 += __shfl_xor(b2, 1, 64); b2 += __shfl_xor(b2, 2, 64);
        if (bg == 0) {
            float nf = (float)(bl + 1);
            float cs  = (b1 + rw1[bi]) * rcpf(nf);
            float csr = (b2 + rw2[bi]) * rcpf(nf);
            csr = fminf(fmaxf(csr, -1.f), 1.f);
            float e = __expf(csr);
            float sal = sigf(cs);
            s2l[bi] = lsi[bi] * rcpf(nf) * sal;
            le[bi] = e;
        }
    }
    __syncthreads();
    if (t < 64) {           // inclusive chunk-local scan of e
        float run = le[t];
#pragma unroll
        for (int off = 1; off < 64; off <<= 1) {
            float o = __shfl_up(run, off, 64);
            if (t >= off) run += o;
        }
        ecum[t] = run;
    }
    __syncthreads();
    if (t == 0) {           // publish {MAGIC, Tcs} as one u64 flag (LDS-sourced, no drain)
        unsigned long long pv = ((unsigned long long)FLAG_MAGIC << 32)
                              | (unsigned long long)__float_as_uint(ecum[63]);
        __hip_atomic_store(&f2[b], pv, __ATOMIC_RELAXED, __HIP_MEMORY_SCOPE_AGENT);
    }

    // local work covering the layer-2 wait: skB -> K^T transpose into stB
    {
        int i0 = (t & 15) * 4, dt = (t >> 4) * 4;
        uint2 kr[4];
#pragma unroll
        for (int r = 0; r < 4; r++) kr[r] = *(const uint2*)&skB[(i0 + r) * SB + dt];
#pragma unroll
        for (int u = 0; u < 4; u++) {
            unsigned int e0 = (u < 2 ? kr[0].x : kr[0].y), e1 = (u < 2 ? kr[1].x : kr[1].y);
            unsigned int e2 = (u < 2 ? kr[2].x : kr[2].y), e3 = (u < 2 ? kr[3].x : kr[3].y);
            int sh = (u & 1) * 16;
            unsigned int lo = ((e0 >> sh) & 0xffffu) | (((e1 >> sh) & 0xffffu) << 16);
            unsigned int hi = ((e2 >> sh) & 0xffffu) | (((e3 >> sh) & 0xffffu) << 16);
            *(uint2*)&stB[(dt + u) * SB + i0] = make_uint2(lo, hi);
        }
    }

    // ---------------- layer-2 lookback: poll returns Tcs values directly -------------
    if (t < 64) {
        bool need = (t < c);
        float tv = 0.f;
        for (;;) {
            unsigned long long x = need
                ? __hip_atomic_load(&f2[s * NC + t], __ATOMIC_RELAXED, __HIP_MEMORY_SCOPE_AGENT)
                : ((unsigned long long)FLAG_MAGIC << 32);
            if (__all((unsigned int)(x >> 32) == FLAG_MAGIC)) {
                tv = need ? __uint_as_float((unsigned int)x) : 0.f;
                break;
            }
            __builtin_amdgcn_s_sleep(2);
        }
        float v = waveRed(tv);          // same lane values -> bit-identical pcsv
        if (t == 0) pcsv = v;
    }
    __syncthreads();
    asm volatile("" ::: "memory");

    // ---------------- Phase D: lsc -> KVT MFMA (inline-scaled A) -> f3 ----------------
    if (t < 64) {
        int l = c * C + t;
        lsc[t] = le[t] * rcpf(pcsv + ecum[t]) * (float)(l + 1);
    }
    __syncthreads();

    {   // MFMA: KVT[m][d] = sum_i bf16(vraw[m][i]*lsc[i]) * K^T[d][i]; A scaled inline
        f32x4 acc[4] = {{0,0,0,0},{0,0,0,0},{0,0,0,0},{0,0,0,0}};
#pragma unroll
        for (int kk = 0; kk < 64; kk += 32) {
            short8 av = *(const short8*)&vsT[(I0 + mf) * SB + kk + qq * 8];
            short8 a;
#pragma unroll
            for (int u = 0; u < 8; u++)
                a[u] = (short)f2bf(bf2f((unsigned short)av[u]) * lsc[kk + qq * 8 + u]);
#pragma unroll
            for (int J = 0; J < 4; J++) {
                short8 bb = *(const short8*)&stB[(16 * J + mf) * SB + kk + qq * 8];
                acc[J] = MFMA16(a, bb, acc[J]);
            }
        }
#pragma unroll
        for (int J = 0; J < 4; J++)
#pragma unroll
            for (int r = 0; r < 4; r++)
                pubf(&KVT[(size_t)b * 4096 + (I0 + 4 * qq + r) * 64 + 16 * J + mf],
                     acc[J][r]);
    }
    publish_flag(&f3[b], t);

    {   // masked P*scomp -> stB (overwrites K^T; fenced by f3's barrier)
        int i = t >> 2, g = t & 3;
        unsigned int wds[8];
#pragma unroll
        for (int p = 0; p < 8; p++) {
            int j0 = g * 16 + 2 * p;
            float v0 = (j0     <= i) ? P[i * SRP + j0]     * lsc[j0]     : 0.f;
            float v1 = (j0 + 1 <= i) ? P[i * SRP + j0 + 1] * lsc[j0 + 1] : 0.f;
            wds[p] = pack2(v0, v1);
        }
        *(uint4*)&stB[i * SB + g * 16]     = make_uint4(wds[0], wds[1], wds[2], wds[3]);
        *(uint4*)&stB[i * SB + g * 16 + 8] = make_uint4(wds[4], wds[5], wds[6], wds[7]);
    }
    __syncthreads();

    // ---------------- Phase F local mm2 (covers the f3-all straggler window) --------
    f32x4 acc[4] = {{0,0,0,0},{0,0,0,0},{0,0,0,0},{0,0,0,0}};
#pragma unroll
    for (int kk = 0; kk < 64; kk += 32) {   // mm2: stB(masked P*scomp) · v  (local)
        short8 a2 = *(const short8*)&stB[(I0 + mf) * SB + kk + qq * 8];
#pragma unroll
        for (int J = 0; J < 4; J++) {
            short8 b2 = *(const short8*)&vsT[(16 * J + mf) * SB + kk + qq * 8];
            acc[J] = MFMA16(a2, b2, acc[J]);
        }
    }

    // ---------------- Phase E: spread KVT exclusive prefix (slice c, 128 elems) -----
    wait_n(&f3[s * NC], NC, t);
    if (t < 64) {
        int e0 = c * 128 + 2 * t;
        float2 x[NC];
#pragma unroll
        for (int cp = 0; cp < NC; cp++) {
            unsigned long long v = rd64(&KVT[(size_t)(s * NC + cp) * 4096 + e0]);
            x[cp].x = __uint_as_float((unsigned int)v);
            x[cp].y = __uint_as_float((unsigned int)(v >> 32));
        }
        float r0 = 0.f, r1p = 0.f;
#pragma unroll
        for (int cp = 0; cp < NC; cp++) {
            pubu((unsigned int*)&KVpb[(size_t)(s * NC + cp) * 4096 + e0], pack2(r0, r1p));
            r0 += x[cp].x; r1p += x[cp].y;
        }
    }
    publish_flag(&f4[b], t);

    // ---------------- Phase F tail: wait f4 (c>0), overlay KVp, mm1 ----------------
    unsigned long long kvp[4];
    if (c > 0) {
        wait_n(&f4[s * NC], NC, t);
        size_t base = (size_t)b * 4096;
#pragma unroll
        for (int j = 0; j < 2; j++) {
            kvp[2 * j]     = rd64(&KVpb[base + 8 * t + 2048 * j]);
            kvp[2 * j + 1] = rd64(&KVpb[base + 8 * t + 2048 * j + 4]);
        }
    } else {
        // exclusive prefix of chunk 0 is identically pack2(0,0) rows
        kvp[0] = kvp[1] = kvp[2] = kvp[3] = 0ull;
    }
#pragma unroll
    for (int j = 0; j < 2; j++) {   // overlay KV-prefix rows [m][d] onto skB
        int flat = 8 * t + 2048 * j, i = flat >> 6, d0 = flat & 63;
        *(uint2*)&skB[i * SB + d0] =
            make_uint2((unsigned int)kvp[2 * j], (unsigned int)(kvp[2 * j] >> 32));
        *(uint2*)&skB[i * SB + d0 + 4] =
            make_uint2((unsigned int)kvp[2 * j + 1], (unsigned int)(kvp[2 * j + 1] >> 32));
    }
    __syncthreads();

#pragma unroll
    for (int kk = 0; kk < 64; kk += 32) {   // mm1: sq · KVp
        short8 a1 = *(const short8*)&sqB[(I0 + mf) * SB + kk + qq * 8];
#pragma unroll
        for (int J = 0; J < 4; J++) {
            short8 b1 = *(const short8*)&skB[(16 * J + mf) * SB + kk + qq * 8];
            acc[J] = MFMA16(a1, b1, acc[J]);
        }
    }
#pragma unroll
    for (int J = 0; J < 4; J++)
#pragma unroll
        for (int r = 0; r < 4; r++) {
            int io = I0 + 4 * qq + r;
            Out[gidx(n, c * C + io, h, 16 * J + mf)] = acc[J][r] * s2l[io];
        }
}

extern "C" void kernel_launch(void* const* d_in, const int* in_sizes, int n_in,
                              void* d_out, int out_size, void* d_ws, size_t ws_size,
                              hipStream_t stream) {
    const float* Q = (const float*)d_in[0];
    const float* K = (const float*)d_in[1];
    const float* V = (const float*)d_in[2];
    float* Out = (float*)d_out;

    float* ws   = (float*)d_ws;
    float* SK   = ws;                   // SC*64
    float* SQ   = SK   + SC * 64;
    float* SKso = SQ   + SC * 64;
    float* SQsi = SKso + SC * 64;
    float* KVT  = SQsi + SC * 64;       // SC*4096 f32
    unsigned short* KVpb = (unsigned short*)(KVT + (size_t)SC * 4096);  // SC*4096 bf16
    unsigned long long* f2 = (unsigned long long*)(KVpb + (size_t)SC * 4096); // SC u64
    unsigned int* f0 = (unsigned int*)(f2 + SC);    // SC each
    unsigned int* f1 = f0 + SC;
    unsigned int* f3 = f1 + SC;
    unsigned int* f4 = f3 + SC;

    k_all<<<SC, 256, 0, stream>>>(Q, K, V, SK, SQ, SKso, SQsi, KVT, KVpb, Out,
                                  f0, f1, f2, f3, f4);
}

// Round 13
// 90.694 us; speedup vs baseline: 1.0408x; 1.0031x over previous
//
#include <hip/hip_runtime.h>
#include <math.h>

// Problem constants (fixed by reference setup_inputs)
constexpr int Nn = 2, Hh = 8, Ll = 2048, Dd = 64;
constexpr int S  = Nn * Hh;      // 16 sequences
constexpr int C  = 64;           // chunk length
constexpr int NC = Ll / C;       // 32 chunks/seq
constexpr int SC = S * NC;       // 512 chunk-blocks

constexpr int SB  = 72;          // bf16 LDS row stride (144 B rows, 16B-aligned)
constexpr int SRP = 65;          // fp32 score-matrix stride
constexpr int SS8 = 9;           // stride for 8-partial row-sum scratch

#define EPSF 1e-6f
#define FLAG_MAGIC 0x5F3A9D21u

typedef __attribute__((ext_vector_type(8))) short short8;
typedef __attribute__((ext_vector_type(4))) float f32x4;
#define MFMA16(a, b, c) __builtin_amdgcn_mfma_f32_16x16x32_bf16(a, b, c, 0, 0, 0)

__device__ __forceinline__ float rcpf(float x) { return __builtin_amdgcn_rcpf(x); }
__device__ __forceinline__ float sigf(float x) { return rcpf(1.0f + __expf(-x)); }

__device__ __forceinline__ float waveRed(float v) {
#pragma unroll
    for (int off = 32; off > 0; off >>= 1) v += __shfl_xor(v, off, 64);
    return v;
}

__device__ __forceinline__ int gidx(int n, int l, int h, int d) {
    return ((n * Ll + l) * Hh + h) * Dd + d;
}

__device__ __forceinline__ float fc(const float4& v, int u) { return ((const float*)&v)[u]; }

__device__ __forceinline__ unsigned short f2bf(float x) {
    unsigned int u = __float_as_uint(x);
    unsigned int r = (u + 0x7fffu + ((u >> 16) & 1u)) >> 16;   // RNE
    return (unsigned short)r;
}
__device__ __forceinline__ unsigned int pack2(float lo, float hi) {
    return (unsigned int)f2bf(lo) | ((unsigned int)f2bf(hi) << 16);
}
__device__ __forceinline__ float bf2f(unsigned short u) {
    return __uint_as_float(((unsigned int)u) << 16);
}
__device__ __forceinline__ float lo16(unsigned int x) { return __uint_as_float(x << 16); }
__device__ __forceinline__ float hi16(unsigned int x) { return __uint_as_float(x & 0xffff0000u); }
__device__ __forceinline__ void unpack8(const uint4& v, float* o) {
    o[0] = lo16(v.x); o[1] = hi16(v.x); o[2] = lo16(v.y); o[3] = hi16(v.y);
    o[4] = lo16(v.z); o[5] = hi16(v.z); o[6] = lo16(v.w); o[7] = hi16(v.w);
}

// ---- agent-scope coherent publish/read (write-through to LLC; no cache-wide inv) ----
__device__ __forceinline__ void pubf(float* p, float v) {
    __hip_atomic_store((unsigned int*)p, __float_as_uint(v),
                       __ATOMIC_RELAXED, __HIP_MEMORY_SCOPE_AGENT);
}
__device__ __forceinline__ float rdf(const float* p) {
    return __uint_as_float(__hip_atomic_load((const unsigned int*)p,
                       __ATOMIC_RELAXED, __HIP_MEMORY_SCOPE_AGENT));
}
__device__ __forceinline__ void pubu(unsigned int* p, unsigned int v) {
    __hip_atomic_store(p, v, __ATOMIC_RELAXED, __HIP_MEMORY_SCOPE_AGENT);
}
__device__ __forceinline__ unsigned long long rd64(const void* p) {
    return __hip_atomic_load((const unsigned long long*)p,
                             __ATOMIC_RELAXED, __HIP_MEMORY_SCOPE_AGENT);
}
// All 256 threads: drain own VMEM, block-barrier, then t==0 sets the flag.
__device__ __forceinline__ void publish_flag(unsigned int* f, int t) {
    asm volatile("s_waitcnt vmcnt(0)" ::: "memory");
    __syncthreads();
    if (t == 0)
        __hip_atomic_store(f, FLAG_MAGIC, __ATOMIC_RELAXED, __HIP_MEMORY_SCOPE_AGENT);
}
// Wave 0 polls n flags at f[0..n); all waves sync after. n <= 64.
__device__ __forceinline__ void wait_n(const unsigned int* f, int n, int t) {
    if (t < 64) {
        const bool need = (t < n);
        for (;;) {
            unsigned int v = need
                ? __hip_atomic_load(&f[t], __ATOMIC_RELAXED, __HIP_MEMORY_SCOPE_AGENT)
                : FLAG_MAGIC;
            if (__all(v == FLAG_MAGIC)) break;
            __builtin_amdgcn_s_sleep(1);
        }
    }
    __syncthreads();
    asm volatile("" ::: "memory");   // no load hoisting above the poll
}

// ============================================================================
// Single persistent kernel (R12 structure). R13: poll sleep 2 -> 1; mm1's sqB
// A-fragments preloaded to registers before the f4 wait (skB overlay doesn't
// touch sqB -> safe). All arithmetic bit-identical to R12.
// LDS 63.5 KB (static limit 64 KB). 2 blocks/CU -> all 512 co-resident.
// ============================================================================
__global__ __launch_bounds__(256, 2) void k_all(
        const float* __restrict__ Q, const float* __restrict__ K,
        const float* __restrict__ V,
        float* __restrict__ SK, float* __restrict__ SQ,
        float* __restrict__ SKso, float* __restrict__ SQsi,
        float* __restrict__ KVT, unsigned short* __restrict__ KVpb,
        float* __restrict__ Out,
        unsigned int* __restrict__ f0, unsigned int* __restrict__ f1,
        unsigned long long* __restrict__ f2, unsigned int* __restrict__ f3,
        unsigned int* __restrict__ f4) {
    __shared__ __align__(16) unsigned short sqB[C * SB];   // sigmoid(Q) rows [i][d]   (A..F)
    __shared__ __align__(16) unsigned short skB[C * SB];   // sigmoid(K) rows; F: KV-prefix rows
    __shared__ __align__(16) unsigned short vsT[C * SB];   // raw V^T [m][i]           (A..F)
    __shared__ __align__(16) unsigned short stB[C * SB];   // D: K^T; then masked P*scomp bf16
    __shared__ __align__(16) float Pun[4608];              // A: scratch; B..D: P scores
    __shared__ float scrA[C * SS8], scrB[C * SS8];
    __shared__ float colK[C], colQ[C], pk[Dd], pq[Dd];
    __shared__ float lsi[C], lso[C], rw1[C], rw2[C], le[C], ecum[C], lsc[C], s2l[C];
    __shared__ float pcsv;

    const int b = blockIdx.x, s = b / NC, c = b % NC;
    const int n = s / Hh, h = s % Hh, t = threadIdx.x;
    const int w = t >> 6, lane = t & 63, mf = lane & 15, qq = lane >> 4;
    const int I0 = 16 * w;
    float* P = Pun;

    // ---------------- Phase A: stage Q/K, publish SK/SQ ASAP ----------------
    {
        int d0 = (4 * t) & 63, ig = t >> 4;
        float psk[4] = {0, 0, 0, 0}, psq[4] = {0, 0, 0, 0};
#pragma unroll
        for (int j = 0; j < 4; j++) {
            int i = ig + 16 * j;
            int id = gidx(n, c * C + i, h, d0);
            float4 q4 = *(const float4*)&Q[id];
            float4 k4 = *(const float4*)&K[id];
            float a0 = sigf(q4.x), a1 = sigf(q4.y), a2 = sigf(q4.z), a3 = sigf(q4.w);
            float b0 = sigf(k4.x), b1 = sigf(k4.y), b2 = sigf(k4.z), b3 = sigf(k4.w);
            *(uint2*)&sqB[i * SB + d0] = make_uint2(pack2(a0, a1), pack2(a2, a3));
            *(uint2*)&skB[i * SB + d0] = make_uint2(pack2(b0, b1), pack2(b2, b3));
            psq[0] += a0; psq[1] += a1; psq[2] += a2; psq[3] += a3;
            psk[0] += b0; psk[1] += b1; psk[2] += b2; psk[3] += b3;
        }
#pragma unroll
        for (int r = 0; r < 4; r++) {
            P[ig * 64 + d0 + r] = psk[r];
            P[1024 + ig * 64 + d0 + r] = psq[r];
        }
    }
    __syncthreads();
    if (t < 64) {
        float v = 0.f;
#pragma unroll
        for (int g = 0; g < 16; g++) v += P[g * 64 + t];
        pubf(&SK[b * 64 + t], v);
    } else if (t < 128) {
        int d = t - 64; float v = 0.f;
#pragma unroll
        for (int g = 0; g < 16; g++) v += P[1024 + g * 64 + d];
        pubf(&SQ[b * 64 + d], v);
    }
    publish_flag(&f0[b], t);

    // V staging AFTER the flag (not needed until D/F)
    {
        int i0 = (t & 15) * 4, dt = (t >> 4) * 4;
        float4 vr[4];
#pragma unroll
        for (int r = 0; r < 4; r++)
            vr[r] = *(const float4*)&V[gidx(n, c * C + i0 + r, h, dt)];
#pragma unroll
        for (int u = 0; u < 4; u++)
            *(uint2*)&vsT[(dt + u) * SB + i0] = make_uint2(
                pack2(fc(vr[0], u), fc(vr[1], u)), pack2(fc(vr[2], u), fc(vr[3], u)));
    }

    // ---------------- Phase B local pre-work (flag-independent) ----------------
#pragma unroll
    for (int j = 0; j < 2; j++) {   // per-row 8-partial sums from LDS tiles
        int flat = 8 * t + 2048 * j, i = flat >> 6, d0 = flat & 63;
        uint4 xq = *(const uint4*)&sqB[i * SB + d0];
        uint4 xk = *(const uint4*)&skB[i * SB + d0];
        float qa[8], ka[8];
        unpack8(xq, qa); unpack8(xk, ka);
        float sq = 0.f, sk = 0.f;
#pragma unroll
        for (int u = 0; u < 8; u++) { sq += qa[u]; sk += ka[u]; }
        scrB[i * SS8 + (d0 >> 3)] = sq;
        scrA[i * SS8 + (d0 >> 3)] = sk;
    }
    __syncthreads();
    if (t < 64) {
        float v = 0.f;
#pragma unroll
        for (int u = 0; u < 8; u++) v += scrA[t * SS8 + u];
        colK[t] = v;
    } else if (t < 128) {
        int i = t - 64; float v = 0.f;
#pragma unroll
        for (int u = 0; u < 8; u++) v += scrB[i * SS8 + u];
        colQ[i] = v;
    }
    __syncthreads();        // colK/colQ ready

    {   // MFMA: P = sq · sk^T (kept in LDS through phase D)
        f32x4 acc[4] = {{0,0,0,0},{0,0,0,0},{0,0,0,0},{0,0,0,0}};
#pragma unroll
        for (int kk = 0; kk < 64; kk += 32) {
            short8 a = *(const short8*)&sqB[(I0 + mf) * SB + kk + qq * 8];
#pragma unroll
            for (int J = 0; J < 4; J++) {
                short8 bb = *(const short8*)&skB[(16 * J + mf) * SB + kk + qq * 8];
                acc[J] = MFMA16(a, bb, acc[J]);
            }
        }
#pragma unroll
        for (int J = 0; J < 4; J++)
#pragma unroll
            for (int r = 0; r < 4; r++)
                P[(I0 + 4 * qq + r) * SRP + 16 * J + mf] = acc[J][r];
    }
    __syncthreads();

    const int bi = t >> 2, bg = t & 3, bl = c * C + bi;
    // register-cache the sq/sk rows consumed by B's and C's dot products
    const uint4 qrow0 = *(const uint4*)&sqB[bi * SB + bg * 16];
    const uint4 qrow1 = *(const uint4*)&sqB[bi * SB + bg * 16 + 8];
    const uint4 krow0 = *(const uint4*)&skB[bi * SB + bg * 16];
    const uint4 krow1 = *(const uint4*)&skB[bi * SB + bg * 16 + 8];

    float prow[16], pcol[16];
    float r1 = 0.f, r2 = 0.f;
#pragma unroll
    for (int u = 0; u < 16; u++) {      // local triangular scans, reg-cached
        int jj = bg + 4 * u;
        prow[u] = P[bi * SRP + jj] + EPSF * colK[jj];
        pcol[u] = P[jj * SRP + bi] + EPSF * colQ[jj];
        bool ok = (jj <= bi);
        r1 += ok ? prow[u] : 0.f;
        r2 += ok ? pcol[u] : 0.f;
    }
    r1 += __shfl_xor(r1, 1, 64); r1 += __shfl_xor(r1, 2, 64);
    r2 += __shfl_xor(r2, 1, 64); r2 += __shfl_xor(r2, 2, 64);

    // ---------------- layer-0 lookback (covered by the local work above) ----------
    wait_n(&f0[s * NC], c, t);

    // ---------------- Phase B dependent tail ----------------
    if (t < 128) {
        const float* src = (t < 64) ? SK : SQ;
        int d = t & 63;
        float p0 = 0.f, p1 = 0.f, p2 = 0.f, p3 = 0.f;
#pragma unroll
        for (int u = 0; u < 8; u++) {
            float v0 = rdf(&src[(s * NC + (0 + 4 * u)) * 64 + d]);
            float v1 = rdf(&src[(s * NC + (1 + 4 * u)) * 64 + d]);
            float v2 = rdf(&src[(s * NC + (2 + 4 * u)) * 64 + d]);
            float v3 = rdf(&src[(s * NC + (3 + 4 * u)) * 64 + d]);
            p0 += (0 + 4 * u < c) ? v0 : 0.f;
            p1 += (1 + 4 * u < c) ? v1 : 0.f;
            p2 += (2 + 4 * u < c) ? v2 : 0.f;
            p3 += (3 + 4 * u < c) ? v3 : 0.f;
        }
        float r = ((p0 + p1) + p2) + p3;
        if (t < 64) pk[d] = r; else pq[d] = r;
    }
    __syncthreads();
    {
        float qa[16], ka[16];
        unpack8(qrow0, qa); unpack8(qrow1, qa + 8);
        unpack8(krow0, ka); unpack8(krow1, ka + 8);
        float b1 = 0.f, b2 = 0.f;
#pragma unroll
        for (int u = 0; u < 16; u++) {
            int d = bg * 16 + u;
            b1 += (qa[u] + EPSF) * (pk[d] + EPSF);
            b2 += (ka[u] + EPSF) * (pq[d] + EPSF);
        }
        b1 += __shfl_xor(b1, 1, 64); b1 += __shfl_xor(b1, 2, 64);
        b2 += __shfl_xor(b2, 1, 64); b2 += __shfl_xor(b2, 2, 64);
        if (bg == 0) {
            float nf = (float)(bl + 1);
            lsi[bi] = nf * rcpf(b1 + r1);
            lso[bi] = nf * rcpf(b2 + r2);
        }
    }
    __syncthreads();
    {   // SKso/SQsi -> publish (flag first; rw1/rw2 moved off-path below)
        int d = t >> 2, g = t & 3;
        float v1 = 0.f, v2 = 0.f;
#pragma unroll
        for (int u = 0; u < 16; u++) {
            int i = g * 16 + u;
            v1 += bf2f(skB[i * SB + d]) * lso[i];
            v2 += bf2f(sqB[i * SB + d]) * lsi[i];
        }
        v1 += __shfl_xor(v1, 1, 64); v1 += __shfl_xor(v1, 2, 64);
        v2 += __shfl_xor(v2, 1, 64); v2 += __shfl_xor(v2, 2, 64);
        if (g == 0) {
            pubf(&SKso[b * 64 + d], v1);
            pubf(&SQsi[b * 64 + d], v2);
        }
    }
    publish_flag(&f1[b], t);

    {   // rw1/rw2 from cached registers (local; covers the f1-layer wait)
        float a1 = 0.f, a2 = 0.f;
#pragma unroll
        for (int u = 0; u < 16; u++) {
            int jj = bg + 4 * u;
            float t1 = lso[jj] * prow[u];
            float t2 = lsi[jj] * pcol[u];
            bool ok = (jj <= bi);
            a1 += ok ? t1 : 0.f;
            a2 += ok ? t2 : 0.f;
        }
        a1 += __shfl_xor(a1, 1, 64); a1 += __shfl_xor(a1, 2, 64);
        a2 += __shfl_xor(a2, 1, 64); a2 += __shfl_xor(a2, 2, 64);
        if (bg == 0) { rw1[bi] = a1; rw2[bi] = a2; }
    }

    // ---------------- layer-1 lookback ----------------
    wait_n(&f1[s * NC], c, t);

    // ---------------- Phase C: cs/csr, e, s2, ecum; Tcs packed into f2 ----------------
    if (t < 128) {
        const float* src = (t < 64) ? SKso : SQsi;
        int d = t & 63;
        float p0 = 0.f, p1 = 0.f, p2 = 0.f, p3 = 0.f;
#pragma unroll
        for (int u = 0; u < 8; u++) {
            float v0 = rdf(&src[(s * NC + (0 + 4 * u)) * 64 + d]);
            float v1 = rdf(&src[(s * NC + (1 + 4 * u)) * 64 + d]);
            float v2 = rdf(&src[(s * NC + (2 + 4 * u)) * 64 + d]);
            float v3 = rdf(&src[(s * NC + (3 + 4 * u)) * 64 + d]);
            p0 += (0 + 4 * u < c) ? v0 : 0.f;
            p1 += (1 + 4 * u < c) ? v1 : 0.f;
            p2 += (2 + 4 * u < c) ? v2 : 0.f;
            p3 += (3 + 4 * u < c) ? v3 : 0.f;
        }
        float r = ((p0 + p1) + p2) + p3;
        if (t < 64) pk[d] = r; else pq[d] = r;
    }
    __syncthreads();
    {
        float qa[16], ka[16];
        unpack8(qrow0, qa); unpack8(qrow1, qa + 8);
        unpack8(krow0, ka); unpack8(krow1, ka + 8);
        float b1 = 0.f, b2 = 0.f;
#pragma unroll
        for (int u = 0; u < 16; u++) {
            int d = bg * 16 + u;
            b1 += (qa[u] + EPSF) * (pk[d] + EPSF);
            b2 += (ka[u] + EPSF) * (pq[d] + EPSF);
        }
        b1 += __shfl_xor(b1, 1, 64); b1 += __shfl_xor(b1, 2, 64);
        b2 += __shfl_xor(b2, 1, 64); b2 += __shfl_xor(b2, 2, 64);
        if (bg == 0) {
            float nf = (float)(bl + 1);
            float cs  = (b1 + rw1[bi]) * rcpf(nf);
            float csr = (b2 + rw2[bi]) * rcpf(nf);
            csr = fminf(fmaxf(csr, -1.f), 1.f);
            float e = __expf(csr);
            float sal = sigf(cs);
            s2l[bi] = lsi[bi] * rcpf(nf) * sal;
            le[bi] = e;
        }
    }
    __syncthreads();
    if (t < 64) {           // inclusive chunk-local scan of e
        float run = le[t];
#pragma unroll
        for (int off = 1; off < 64; off <<= 1) {
            float o = __shfl_up(run, off, 64);
            if (t >= off) run += o;
        }
        ecum[t] = run;
    }
    __syncthreads();
    if (t == 0) {           // publish {MAGIC, Tcs} as one u64 flag (LDS-sourced, no drain)
        unsigned long long pv = ((unsigned long long)FLAG_MAGIC << 32)
                              | (unsigned long long)__float_as_uint(ecum[63]);
        __hip_atomic_store(&f2[b], pv, __ATOMIC_RELAXED, __HIP_MEMORY_SCOPE_AGENT);
    }

    // local work covering the layer-2 wait: skB -> K^T transpose into stB
    {
        int i0 = (t & 15) * 4, dt = (t >> 4) * 4;
        uint2 kr[4];
#pragma unroll
        for (int r = 0; r < 4; r++) kr[r] = *(const uint2*)&skB[(i0 + r) * SB + dt];
#pragma unroll
        for (int u = 0; u < 4; u++) {
            unsigned int e0 = (u < 2 ? kr[0].x : kr[0].y), e1 = (u < 2 ? kr[1].x : kr[1].y);
            unsigned int e2 = (u < 2 ? kr[2].x : kr[2].y), e3 = (u < 2 ? kr[3].x : kr[3].y);
            int sh = (u & 1) * 16;
            unsigned int lo = ((e0 >> sh) & 0xffffu) | (((e1 >> sh) & 0xffffu) << 16);
            unsigned int hi = ((e2 >> sh) & 0xffffu) | (((e3 >> sh) & 0xffffu) << 16);
            *(uint2*)&stB[(dt + u) * SB + i0] = make_uint2(lo, hi);
        }
    }

    // ---------------- layer-2 lookback: poll returns Tcs values directly -------------
    if (t < 64) {
        bool need = (t < c);
        float tv = 0.f;
        for (;;) {
            unsigned long long x = need
                ? __hip_atomic_load(&f2[s * NC + t], __ATOMIC_RELAXED, __HIP_MEMORY_SCOPE_AGENT)
                : ((unsigned long long)FLAG_MAGIC << 32);
            if (__all((unsigned int)(x >> 32) == FLAG_MAGIC)) {
                tv = need ? __uint_as_float((unsigned int)x) : 0.f;
                break;
            }
            __builtin_amdgcn_s_sleep(1);
        }
        float v = waveRed(tv);          // same lane values -> bit-identical pcsv
        if (t == 0) pcsv = v;
    }
    __syncthreads();
    asm volatile("" ::: "memory");

    // ---------------- Phase D: lsc -> KVT MFMA (inline-scaled A) -> f3 ----------------
    if (t < 64) {
        int l = c * C + t;
        lsc[t] = le[t] * rcpf(pcsv + ecum[t]) * (float)(l + 1);
    }
    __syncthreads();

    {   // MFMA: KVT[m][d] = sum_i bf16(vraw[m][i]*lsc[i]) * K^T[d][i]; A scaled inline
        f32x4 acc[4] = {{0,0,0,0},{0,0,0,0},{0,0,0,0},{0,0,0,0}};
#pragma unroll
        for (int kk = 0; kk < 64; kk += 32) {
            short8 av = *(const short8*)&vsT[(I0 + mf) * SB + kk + qq * 8];
            short8 a;
#pragma unroll
            for (int u = 0; u < 8; u++)
                a[u] = (short)f2bf(bf2f((unsigned short)av[u]) * lsc[kk + qq * 8 + u]);
#pragma unroll
            for (int J = 0; J < 4; J++) {
                short8 bb = *(const short8*)&stB[(16 * J + mf) * SB + kk + qq * 8];
                acc[J] = MFMA16(a, bb, acc[J]);
            }
        }
#pragma unroll
        for (int J = 0; J < 4; J++)
#pragma unroll
            for (int r = 0; r < 4; r++)
                pubf(&KVT[(size_t)b * 4096 + (I0 + 4 * qq + r) * 64 + 16 * J + mf],
                     acc[J][r]);
    }
    publish_flag(&f3[b], t);

    {   // masked P*scomp -> stB (overwrites K^T; fenced by f3's barrier)
        int i = t >> 2, g = t & 3;
        unsigned int wds[8];
#pragma unroll
        for (int p = 0; p < 8; p++) {
            int j0 = g * 16 + 2 * p;
            float v0 = (j0     <= i) ? P[i * SRP + j0]     * lsc[j0]     : 0.f;
            float v1 = (j0 + 1 <= i) ? P[i * SRP + j0 + 1] * lsc[j0 + 1] : 0.f;
            wds[p] = pack2(v0, v1);
        }
        *(uint4*)&stB[i * SB + g * 16]     = make_uint4(wds[0], wds[1], wds[2], wds[3]);
        *(uint4*)&stB[i * SB + g * 16 + 8] = make_uint4(wds[4], wds[5], wds[6], wds[7]);
    }
    __syncthreads();

    // ---------------- Phase F local mm2 (covers the f3-all straggler window) --------
    f32x4 acc[4] = {{0,0,0,0},{0,0,0,0},{0,0,0,0},{0,0,0,0}};
#pragma unroll
    for (int kk = 0; kk < 64; kk += 32) {   // mm2: stB(masked P*scomp) · v  (local)
        short8 a2 = *(const short8*)&stB[(I0 + mf) * SB + kk + qq * 8];
#pragma unroll
        for (int J = 0; J < 4; J++) {
            short8 b2 = *(const short8*)&vsT[(16 * J + mf) * SB + kk + qq * 8];
            acc[J] = MFMA16(a2, b2, acc[J]);
        }
    }

    // ---------------- Phase E: spread KVT exclusive prefix (slice c, 128 elems) -----
    wait_n(&f3[s * NC], NC, t);
    if (t < 64) {
        int e0 = c * 128 + 2 * t;
        float2 x[NC];
#pragma unroll
        for (int cp = 0; cp < NC; cp++) {
            unsigned long long v = rd64(&KVT[(size_t)(s * NC + cp) * 4096 + e0]);
            x[cp].x = __uint_as_float((unsigned int)v);
            x[cp].y = __uint_as_float((unsigned int)(v >> 32));
        }
        float r0 = 0.f, r1p = 0.f;
#pragma unroll
        for (int cp = 0; cp < NC; cp++) {
            pubu((unsigned int*)&KVpb[(size_t)(s * NC + cp) * 4096 + e0], pack2(r0, r1p));
            r0 += x[cp].x; r1p += x[cp].y;
        }
    }
    publish_flag(&f4[b], t);

    // preload mm1's sqB A-fragments (LDS; sqB untouched by the overlay) -> covers f4
    short8 a1f[2];
    a1f[0] = *(const short8*)&sqB[(I0 + mf) * SB + 0  + qq * 8];
    a1f[1] = *(const short8*)&sqB[(I0 + mf) * SB + 32 + qq * 8];

    // ---------------- Phase F tail: wait f4 (c>0), overlay KVp, mm1 ----------------
    unsigned long long kvp[4];
    if (c > 0) {
        wait_n(&f4[s * NC], NC, t);
        size_t base = (size_t)b * 4096;
#pragma unroll
        for (int j = 0; j < 2; j++) {
            kvp[2 * j]     = rd64(&KVpb[base + 8 * t + 2048 * j]);
            kvp[2 * j + 1] = rd64(&KVpb[base + 8 * t + 2048 * j + 4]);
        }
    } else {
        // exclusive prefix of chunk 0 is identically pack2(0,0) rows
        kvp[0] = kvp[1] = kvp[2] = kvp[3] = 0ull;
    }
#pragma unroll
    for (int j = 0; j < 2; j++) {   // overlay KV-prefix rows [m][d] onto skB
        int flat = 8 * t + 2048 * j, i = flat >> 6, d0 = flat & 63;
        *(uint2*)&skB[i * SB + d0] =
            make_uint2((unsigned int)kvp[2 * j], (unsigned int)(kvp[2 * j] >> 32));
        *(uint2*)&skB[i * SB + d0 + 4] =
            make_uint2((unsigned int)kvp[2 * j + 1], (unsigned int)(kvp[2 * j + 1] >> 32));
    }
    __syncthreads();

#pragma unroll
    for (int kk = 0; kk < 64; kk += 32) {   // mm1: sq · KVp (A-fragments preloaded)
        short8 a1 = a1f[kk >> 5];
#pragma unroll
        for (int J = 0; J < 4; J++) {
            short8 b1 = *(const short8*)&skB[(16 * J + mf) * SB + kk + qq * 8];
            acc[J] = MFMA16(a1, b1, acc[J]);
        }
    }
#pragma unroll
    for (int J = 0; J < 4; J++)
#pragma unroll
        for (int r = 0; r < 4; r++) {
            int io = I0 + 4 * qq + r;
            Out[gidx(n, c * C + io, h, 16 * J + mf)] = acc[J][r] * s2l[io];
        }
}

extern "C" void kernel_launch(void* const* d_in, const int* in_sizes, int n_in,
                              void* d_out, int out_size, void* d_ws, size_t ws_size,
                              hipStream_t stream) {
    const float* Q = (const float*)d_in[0];
    const float* K = (const float*)d_in[1];
    const float* V = (const float*)d_in[2];
    float* Out = (float*)d_out;

    float* ws   = (float*)d_ws;
    float* SK   = ws;                   // SC*64
    float* SQ   = SK   + SC * 64;
    float* SKso = SQ   + SC * 64;
    float* SQsi = SKso + SC * 64;
    float* KVT  = SQsi + SC * 64;       // SC*4096 f32
    unsigned short* KVpb = (unsigned short*)(KVT + (size_t)SC * 4096);  // SC*4096 bf16
    unsigned long long* f2 = (unsigned long long*)(KVpb + (size_t)SC * 4096); // SC u64
    unsigned int* f0 = (unsigned int*)(f2 + SC);    // SC each
    unsigned int* f1 = f0 + SC;
    unsigned int* f3 = f1 + SC;
    unsigned int* f4 = f3 + SC;

    k_all<<<SC, 256, 0, stream>>>(Q, K, V, SK, SQ, SKso, SQsi, KVT, KVpb, Out,
                                  f0, f1, f2, f3, f4);
}